// Round 13
// baseline (277.023 us; speedup 1.0000x reference)
//
#include <hip/hip_runtime.h>
#include <stdint.h>

#define N_NODES 50000
#define N_EDGES 600000
#define N_REL   8
#define KDIM    1152                      // GEMM K: 8*128 means + 128 self/root
#define KA      1024                      // aggAll row width (means only)
#define NPAD    50048                     // 391 * 128 (= 782 * 64)
#define RCAP    16                        // per-(node,rel) bucket cap (Poisson(1.5): P(>16)~6e-13)
#define ZROW    N_NODES                   // sentinel zero row (written by k_prep)

typedef short v8s __attribute__((ext_vector_type(8)));
typedef float v4f __attribute__((ext_vector_type(4)));
typedef float v2f __attribute__((ext_vector_type(2)));
typedef unsigned short u16;
typedef unsigned int   u32;
typedef __attribute__((address_space(1))) const u32 gas_u32;
typedef __attribute__((address_space(3))) u32 las_u32;

__device__ __forceinline__ float bf2f(u16 u) {
    union { u32 i; float f; } t; t.i = ((u32)u) << 16; return t.f;
}
__device__ __forceinline__ u16 f2bf(float f) {
    union { float f; u32 i; } t; t.f = f;
    u32 lsb = (t.i >> 16) & 1u;
    t.i += 0x7fffu + lsb;            // round-to-nearest-even
    return (u16)(t.i >> 16);
}
// unpack a u32 holding 2 bf16 into (lo,hi) f32 pair: 1 shl + 1 and, no cvt
__device__ __forceinline__ v2f bfpair(u32 g) {
    union { u32 i; float f; } a, b;
    a.i = g << 16; b.i = g & 0xffff0000u;
    return (v2f){a.f, b.f};
}
__device__ __forceinline__ float load_f(const void* p, int i, int fl) {
    return fl ? bf2f(((const u16*)p)[i]) : ((const float*)p)[i];
}
// wave-local dtype detect: every wave reads x32[0..63] (L2-hot broadcast),
// ballots on "bits[14:7] look like a bf16 exponent of N(0,1) data".
__device__ __forceinline__ int wave_detect(const u32* __restrict__ x32) {
    u32 w = x32[threadIdx.x & 63];
    u32 e = (w >> 7) & 0xffu;
    unsigned long long m = __ballot(e >= 112u && e < 144u);
    return __popcll(m) >= 32;        // 1 = bf16, 0 = f32
}

// ---------- K1: count+fill (node,rel) buckets || convert x || prep weights || relemb+zrows ----------
// CF: 1 edge/thread, 2344 blocks (R9 post-mortem: 4 edges/thread REGRESSED 42->52 us —
// quartering CF wave count lost more TLP than per-thread ILP gained; atomic->store
// chains serialize in the memory pipe regardless). R8-measured: 42 us.
// Node-major buckets: cnt[node*8+rel], evalF[(node*8+rel)*RCAP + pos] = src (u16).
// Wbig[l][j][k]: k<1024 -> W_l[k/128][k%128][j]; k>=1024 -> root_l[k-1024][j]
#define B_CF    2344
#define B_CONV  (B_CF + 3125)             // 3125 blk * 256 thr * 8 elems = 6.4M exact
#define B_PREPW (B_CONV + 1153)
#define B_RELEMB (B_PREPW + 5)            // 4 relemb blocks + 1 zero-row block
__global__ void k_prep(const void* __restrict__ x, const int* __restrict__ ei,
                       const int* __restrict__ et,
                       const void* __restrict__ W1, const void* __restrict__ r1,
                       const void* __restrict__ b1, const void* __restrict__ W2,
                       const void* __restrict__ r2, const void* __restrict__ b2,
                       const void* __restrict__ rel_emb,
                       u16* __restrict__ xc, u16* __restrict__ hbuf,
                       u16* __restrict__ Wbig,
                       u16* __restrict__ bc, int* __restrict__ cnt,
                       u16* __restrict__ evalF, void* __restrict__ out) {
    int b = blockIdx.x, tid = threadIdx.x;
    int fl = wave_detect((const u32*)x);
    if (b < B_CF) {
        int i = b * 256 + tid;
        if (i < N_EDGES) {
            int d = ei[N_EDGES + i];
            int bkt = d * N_REL + et[i];
            int pos = atomicAdd(&cnt[bkt], 1);
            if (pos < RCAP) evalF[(size_t)bkt * RCAP + pos] = (u16)ei[i];
        }
    } else if (b < B_CONV) {
        int g = (b - B_CF) * 256 + tid;           // 8-elem group
        if (fl) {
            ((int4*)xc)[g] = ((const int4*)x)[g];
        } else {
            const float* xf = (const float*)x + g * 8;
            u16 o[8];
            #pragma unroll
            for (int j = 0; j < 8; ++j) o[j] = f2bf(xf[j]);
            *(int4*)(xc + g * 8) = *(const int4*)o;
        }
    } else if (b < B_PREPW) {
        int o = (b - B_CONV) * 256 + tid;
        if (o < 2 * 128 * KDIM) {
            int l = o / (128 * KDIM);
            int rem = o - l * (128 * KDIM);
            int j = rem / KDIM, k = rem - j * KDIM;
            float v;
            if (k < 1024) {
                int r = k >> 7, kk = k & 127;
                v = load_f(l ? W2 : W1, r * 16384 + kk * 128 + j, fl);
            } else {
                v = load_f(l ? r2 : r1, (k - 1024) * 128 + j, fl);
            }
            Wbig[o] = f2bf(v);
        } else if (o < 2 * 128 * KDIM + 256) {
            int o2 = o - 2 * 128 * KDIM;
            bc[o2] = f2bf(load_f((o2 >> 7) ? b2 : b1, o2 & 127, fl));
        }
    } else if (b < B_PREPW + 4) {
        int i = (b - B_PREPW) * 256 + tid;
        if (i < N_REL * 128) {
            size_t o = (size_t)N_NODES * 128 + i;
            if (fl) ((u16*)out)[o]   = ((const u16*)rel_emb)[i];
            else    ((float*)out)[o] = ((const float*)rel_emb)[i];
        }
    } else {
        // zero-row sentinels for agg (row ZROW of both feature buffers);
        // replaces two 256-B memset graph nodes
        if (tid < 64)        ((u32*)(xc   + (size_t)ZROW * 128))[tid]      = 0;
        else if (tid < 128)  ((u32*)(hbuf + (size_t)ZROW * 128))[tid - 64] = 0;
    }
}

// ---------- agg: wave-per-node, 8 relation means -> aggAll[NPAD,1024] ----------
// VALU-lean (R8-measured 42 us, 55% VALU, 52% HBM):
// 1) invalid slots gather from the ZERO ROW -> unconditional accumulate;
// 2) 32-bit byte offsets from the uniform feat base;
// 3) bit-trick bf16 unpack into float2 accs; v_cvt_pk_bf16_f32 epilogue.
__global__ __launch_bounds__(256) void k_agg_all(
        const u16* __restrict__ feat,     // [NPAD,128] bf16 (xc or h), row ZROW = 0
        const int* __restrict__ cnt, const u16* __restrict__ evalF,
        u16* __restrict__ aggAll) {
    int wave = threadIdx.x >> 6, lane = threadIdx.x & 63;
    int node = blockIdx.x * 4 + wave;
    if (node >= N_NODES) return;
    u32 lane4 = (u32)lane * 4u;          // byte offset of this lane's dim pair
    int base = node * N_REL;

    // counts (broadcast, 2 x int4)
    int4 ca = ((const int4*)(cnt + base))[0];
    int4 cb = ((const int4*)(cnt + base))[1];
    int cs[8] = {ca.x, ca.y, ca.z, ca.w, cb.x, cb.y, cb.z, cb.w};
    // entries: first 4 slots of each bucket, 8 independent broadcast loads
    const u16* eb = evalF + (size_t)base * RCAP;
    ushort4 eg[8];
    #pragma unroll
    for (int r = 0; r < N_REL; ++r)
        eg[r] = *(const ushort4*)(eb + r * RCAP);

    // 32 gathers (invalid -> zero row), unconditional accumulate
    const char* fb = (const char*)feat;
    v2f acc[N_REL];
    #pragma unroll
    for (int r = 0; r < N_REL; ++r) {
        int c = cs[r];
        u32 o0 = ((u32)(c > 0 ? (int)eg[r].x : ZROW) << 8) + lane4;
        u32 o1 = ((u32)(c > 1 ? (int)eg[r].y : ZROW) << 8) + lane4;
        u32 o2 = ((u32)(c > 2 ? (int)eg[r].z : ZROW) << 8) + lane4;
        u32 o3 = ((u32)(c > 3 ? (int)eg[r].w : ZROW) << 8) + lane4;
        u32 g0 = *(const u32*)(fb + o0);
        u32 g1 = *(const u32*)(fb + o1);
        u32 g2 = *(const u32*)(fb + o2);
        u32 g3 = *(const u32*)(fb + o3);
        acc[r] = (bfpair(g0) + bfpair(g1)) + (bfpair(g2) + bfpair(g3));
    }

    // rare tail: any bucket with c > 4 (wave-uniform condition)
    int cmax = cs[0];
    #pragma unroll
    for (int r = 1; r < N_REL; ++r) cmax = cs[r] > cmax ? cs[r] : cmax;
    if (cmax > 4) {
        #pragma unroll
        for (int r = 0; r < N_REL; ++r) {
            int c = cs[r] < RCAP ? cs[r] : RCAP;
            for (int j = 4; j < c; ++j) {
                u32 oj = ((u32)eb[r * RCAP + j] << 8) + lane4;
                acc[r] += bfpair(*(const u32*)(fb + oj));
            }
        }
    }

    // means -> packed bf16, 8 dword stores (stride 256 B)
    u32* d32 = (u32*)(aggAll + (size_t)node * KA) + lane;
    #pragma unroll
    for (int r = 0; r < N_REL; ++r) {
        int cc = cs[r] < RCAP ? cs[r] : RCAP;
        if (cc < 1) cc = 1;
        // v_rcp_f32: 2^-23 rel error, invisible under bf16 (2^-9) rounding
        float inv = __builtin_amdgcn_rcpf((float)cc);
        float mx = acc[r].x * inv, my = acc[r].y * inv;
        u32 pk;
        asm("v_cvt_pk_bf16_f32 %0, %1, %2" : "=v"(pk) : "v"(mx), "v"(my));
        d32[r * 64] = pk;
    }
}

// ---------- GEMM: out = relu([aggAll | feat] @ Wbig + bias) ----------
// R9 rebalance: BM=128 gave 391 blocks at 2/CU -> 135 CUs run 2 blocks, 121 run 1
// (76% balance, runtime = 2 x T_block). BM=64 -> 782 blocks, LDS 48 KB -> 3/CU
// (782 ~ 3.05 x 256, near-perfect), occupancy 16->24 waves/CU.
// 512 thr, 8 waves in 2x4 grid of 32x32 tiles, acc[2][2]; K=1152 in 9 BK=128 chunks;
// chunk 8's A-slice from feat. Same proven swizzle: stored 16B-unit = k-unit^(row&15).
__global__ __launch_bounds__(512, 6) void k_gemm(
        const u16* __restrict__ A,        // [NPAD,1024] bf16 (means)
        const u16* __restrict__ feat,     // [NPAD,128] bf16 (self/root slice)
        const u16* __restrict__ Bw,       // [128][1152] bf16 (j-major, k contiguous)
        const u16* __restrict__ bias,     // [128]
        const u32* __restrict__ xdet,     // raw x for wave_detect
        u16* __restrict__ hout, void* __restrict__ fout,
        int final_out) {
    __shared__ __align__(16) u16 As[64 * 128];    // 16 KB
    __shared__ __align__(16) u16 Bs[128 * 128];   // 32 KB
    int tid = threadIdx.x;
    int fl = wave_detect(xdet);          // uniform; used only if final_out
    int bm0 = blockIdx.x * 64;           // NPAD/64 = 782 grid
    int wave = tid >> 6, lane = tid & 63;
    int wm = (wave & 1) * 32, wn = (wave >> 1) * 32;
    int lrow = lane & 15, quad = lane >> 4;

    v4f accr[2][2];
    #pragma unroll
    for (int i = 0; i < 2; ++i)
        #pragma unroll
        for (int j = 0; j < 2; ++j) accr[i][j] = (v4f){0.f, 0.f, 0.f, 0.f};

    for (int h = 0; h < 9; ++h) {
        if (h) __syncthreads();           // WAR: all waves done reading LDS
        // ---- As: 2 KB per wave (2 issues), Bs: 4 KB per wave (4 issues) ----
        #pragma unroll
        for (int j = 0; j < 2; ++j) {
            int off = wave * 2048 + j * 1024 + lane * 16;   // byte offset, linear dest
            int row = off >> 8;                              // 256 B per row (0..63)
            int cc = ((off >> 4) & 15) ^ (row & 15);         // inverse of read swizzle
            const u16* srcA = (h < 8)
                ? A + (size_t)(bm0 + row) * KA + h * 128 + cc * 8
                : feat + (size_t)(bm0 + row) * 128 + cc * 8;
            __builtin_amdgcn_global_load_lds((gas_u32*)srcA,
                (las_u32*)(As + (off >> 1) - lane * 8), 16, 0, 0);
        }
        #pragma unroll
        for (int j = 0; j < 4; ++j) {
            int off = wave * 4096 + j * 1024 + lane * 16;   // byte offset (0..32767)
            int row = off >> 8;                              // 0..127
            int cc = ((off >> 4) & 15) ^ (row & 15);
            __builtin_amdgcn_global_load_lds(
                (gas_u32*)(Bw + (size_t)row * KDIM + h * 128 + cc * 8),
                (las_u32*)(Bs + (off >> 1) - lane * 8), 16, 0, 0);
        }
        __syncthreads();                  // drains vmcnt (compiler-inserted)

        #pragma unroll
        for (int kk = 0; kk < 4; ++kk) {
            int chunk = kk * 4 + quad;
            v8s a[2], b[2];
            #pragma unroll
            for (int t = 0; t < 2; ++t) {
                int row = wm + t * 16 + lrow;
                a[t] = *(const v8s*)(As + row * 128 + (chunk ^ (row & 15)) * 8);
            }
            #pragma unroll
            for (int t = 0; t < 2; ++t) {
                int row = wn + t * 16 + lrow;
                b[t] = *(const v8s*)(Bs + row * 128 + (chunk ^ (row & 15)) * 8);
            }
            #pragma unroll
            for (int ti = 0; ti < 2; ++ti)
                #pragma unroll
                for (int tj = 0; tj < 2; ++tj)
                    accr[ti][tj] = __builtin_amdgcn_mfma_f32_16x16x32_bf16(a[ti], b[tj], accr[ti][tj], 0, 0, 0);
        }
    }

    #pragma unroll
    for (int ti = 0; ti < 2; ++ti)
        #pragma unroll
        for (int reg = 0; reg < 4; ++reg) {
            int gm = bm0 + wm + ti * 16 + quad * 4 + reg;
            if (gm >= N_NODES) continue;
            #pragma unroll
            for (int tj = 0; tj < 2; ++tj) {
                int col = wn + tj * 16 + lrow;
                size_t idx = (size_t)gm * 128 + col;
                float v = fmaxf(accr[ti][tj][reg] + bf2f(bias[col]), 0.f);
                if (!final_out) hout[idx] = f2bf(v);
                else if (fl)    ((u16*)fout)[idx] = f2bf(v);
                else            ((float*)fout)[idx] = v;
            }
        }
}

// ---------------- launch ----------------
static inline size_t align_up(size_t x, size_t a) { return (x + a - 1) & ~(a - 1); }

extern "C" void kernel_launch(void* const* d_in, const int* in_sizes, int n_in,
                              void* d_out, int out_size, void* d_ws, size_t ws_size,
                              hipStream_t stream) {
    const int* ei = (const int*)d_in[1];
    const int* et = (const int*)d_in[2];

    char* ws = (char*)d_ws;
    size_t off = 0;
    u16* Wbig   = (u16*)(ws + off);  off = align_up(off + (size_t)2 * 128 * KDIM * 2, 256);
    u16* bc     = (u16*)(ws + off);  off = align_up(off + 512, 256);
    u16* xc     = (u16*)(ws + off);  off = align_up(off + (size_t)NPAD * 128 * 2, 256);
    int* cnt    = (int*)(ws + off);  off = align_up(off + (size_t)N_NODES * N_REL * 4, 256);
    u16* evalF  = (u16*)(ws + off);  off = align_up(off + (size_t)N_NODES * N_REL * RCAP * 2, 256);
    u16* h      = (u16*)(ws + off);  off = align_up(off + (size_t)NPAD * 128 * 2, 256);
    u16* aggAll = (u16*)(ws + off);  off += (size_t)NPAD * KA * 2;   // ~143 MB total
    (void)in_sizes; (void)n_in; (void)out_size; (void)ws_size;   // ws >= 157 MB (verified r3/r4)

    hipMemsetAsync(cnt, 0, (size_t)N_NODES * N_REL * 4, stream);
    k_prep<<<B_RELEMB, 256, 0, stream>>>(d_in[0], ei, et, d_in[3], d_in[4], d_in[5],
                                         d_in[6], d_in[7], d_in[8], d_in[9],
                                         xc, h, Wbig, bc, cnt, evalF, d_out);

    for (int l = 0; l < 2; ++l) {
        const u16* src = l ? h : xc;
        k_agg_all<<<(N_NODES + 3) / 4, 256, 0, stream>>>(src, cnt, evalF, aggAll);
        k_gemm<<<NPAD / 64, 512, 0, stream>>>(aggAll, src, Wbig + (size_t)l * 128 * KDIM,
                                              bc + l * 128, (const u32*)d_in[0],
                                              h, d_out, l);
    }
}

// Round 15
// 263.521 us; speedup vs baseline: 1.0512x; 1.0512x over previous
//
#include <hip/hip_runtime.h>
#include <stdint.h>

#define N_NODES 50000
#define N_EDGES 600000
#define N_REL   8
#define NPLANE  9                         // 8 relation planes + 1 self/root plane
#define NPAD    50048                     // 391 * 128
#define RCAP    16                        // per-(node,rel) bucket cap (Poisson(1.5): P(>16)~6e-13)
#define ZROW    N_NODES                   // sentinel zero row (written by k_prep)
#define PLSZ    (NPAD * 256u)             // Y plane size in bytes (NPAD rows x 256 B)

typedef short v8s __attribute__((ext_vector_type(8)));
typedef float v4f __attribute__((ext_vector_type(4)));
typedef float v2f __attribute__((ext_vector_type(2)));
typedef unsigned short u16;
typedef unsigned int   u32;
typedef __attribute__((address_space(1))) const u32 gas_u32;
typedef __attribute__((address_space(3))) u32 las_u32;

__device__ __forceinline__ float bf2f(u16 u) {
    union { u32 i; float f; } t; t.i = ((u32)u) << 16; return t.f;
}
__device__ __forceinline__ u16 f2bf(float f) {
    union { float f; u32 i; } t; t.f = f;
    u32 lsb = (t.i >> 16) & 1u;
    t.i += 0x7fffu + lsb;            // round-to-nearest-even
    return (u16)(t.i >> 16);
}
// unpack a u32 holding 2 bf16 into (lo,hi) f32 pair: 1 shl + 1 and, no cvt
__device__ __forceinline__ v2f bfpair(u32 g) {
    union { u32 i; float f; } a, b;
    a.i = g << 16; b.i = g & 0xffff0000u;
    return (v2f){a.f, b.f};
}
__device__ __forceinline__ float load_f(const void* p, int i, int fl) {
    return fl ? bf2f(((const u16*)p)[i]) : ((const float*)p)[i];
}
// wave-local dtype detect: every wave reads x32[0..63] (L2-hot broadcast),
// ballots on "bits[14:7] look like a bf16 exponent of N(0,1) data".
__device__ __forceinline__ int wave_detect(const u32* __restrict__ x32) {
    u32 w = x32[threadIdx.x & 63];
    u32 e = (w >> 7) & 0xffu;
    unsigned long long m = __ballot(e >= 112u && e < 144u);
    return __popcll(m) >= 32;        // 1 = bf16, 0 = f32
}

// ---------- K1: count+fill (node,rel) buckets || convert x || prep weights || relemb+zrows ----------
// CF: 1 edge/thread, 2344 blocks (R9: 4 edges/thread regressed 42->52 us). R8-measured: 42 us.
// Node-major buckets: cnt[node*8+rel], evalF[(node*8+rel)*RCAP + pos] = src (u16).
// Wt layout (TRANSFORM-FIRST pipeline): Wt[l][r][j][k] = W_l[r][k][j] for r<8,
// Wt[l][8][j][k] = root_l[k][j] — j-major, k contiguous, per-plane B panels.
#define B_CF    2344
#define B_CONV  (B_CF + 3125)             // 3125 blk * 256 thr * 8 elems = 6.4M exact
#define B_PREPW (B_CONV + 1153)           // 2*9*16384 = 294912 W elems + 256 bias
#define B_RELEMB (B_PREPW + 5)            // 4 relemb blocks + 1 zero-row block
__global__ void k_prep(const void* __restrict__ x, const int* __restrict__ ei,
                       const int* __restrict__ et,
                       const void* __restrict__ W1, const void* __restrict__ r1,
                       const void* __restrict__ b1, const void* __restrict__ W2,
                       const void* __restrict__ r2, const void* __restrict__ b2,
                       const void* __restrict__ rel_emb,
                       u16* __restrict__ xc, u16* __restrict__ hbuf,
                       u16* __restrict__ Wt,
                       u16* __restrict__ bc, int* __restrict__ cnt,
                       u16* __restrict__ evalF, void* __restrict__ out) {
    int b = blockIdx.x, tid = threadIdx.x;
    int fl = wave_detect((const u32*)x);
    if (b < B_CF) {
        int i = b * 256 + tid;
        if (i < N_EDGES) {
            int d = ei[N_EDGES + i];
            int bkt = d * N_REL + et[i];
            int pos = atomicAdd(&cnt[bkt], 1);
            if (pos < RCAP) evalF[(size_t)bkt * RCAP + pos] = (u16)ei[i];
        }
    } else if (b < B_CONV) {
        int g = (b - B_CF) * 256 + tid;           // 8-elem group
        if (fl) {
            ((int4*)xc)[g] = ((const int4*)x)[g];
        } else {
            const float* xf = (const float*)x + g * 8;
            u16 o[8];
            #pragma unroll
            for (int j = 0; j < 8; ++j) o[j] = f2bf(xf[j]);
            *(int4*)(xc + g * 8) = *(const int4*)o;
        }
    } else if (b < B_PREPW) {
        int o = (b - B_CONV) * 256 + tid;
        if (o < 2 * NPLANE * 16384) {
            int l = o / (NPLANE * 16384);
            int rem = o - l * (NPLANE * 16384);
            int rr = rem >> 14;               // plane 0..8
            int j = (rem >> 7) & 127;        // output col
            int k = rem & 127;               // input dim
            float v = (rr < 8)
                ? load_f(l ? W2 : W1, rr * 16384 + k * 128 + j, fl)
                : load_f(l ? r2 : r1, k * 128 + j, fl);
            Wt[o] = f2bf(v);
        } else if (o < 2 * NPLANE * 16384 + 256) {
            int o2 = o - 2 * NPLANE * 16384;
            bc[o2] = f2bf(load_f((o2 >> 7) ? b2 : b1, o2 & 127, fl));
        }
    } else if (b < B_PREPW + 4) {
        int i = (b - B_PREPW) * 256 + tid;
        if (i < N_REL * 128) {
            size_t o = (size_t)N_NODES * 128 + i;
            if (fl) ((u16*)out)[o]   = ((const u16*)rel_emb)[i];
            else    ((float*)out)[o] = ((const float*)rel_emb)[i];
        }
    } else {
        // zero-row sentinels (row ZROW of both feature buffers) -> Y[r][ZROW] = 0@W = 0
        if (tid < 64)        ((u32*)(xc   + (size_t)ZROW * 128))[tid]      = 0;
        else if (tid < 128)  ((u32*)(hbuf + (size_t)ZROW * 128))[tid - 64] = 0;
    }
}

// ---------- transform GEMM: Y[rp] = feat @ Wt[rp] (9 planes, K=128, NO k-loop) ----------
// R13 post-mortem: the old aggregate-then-transform gemm was stall-bound (MfmaUtil 12.5%,
// VALU 13%, HBM 30%): 9x {stage -> barrier -> compute -> barrier}, zero overlap. K=128
// transform-first has ONE stage + ONE barrier + 32 MFMA/wave per block; latency hides via
// 3519 blocks (13.7/CU) turnover. Writes Y planes (means reorder: (sum x)/c @ W = sum(x@W)/c).
// Staging/swizzle/compute blocks reused verbatim from the R8-measured gemm.
__global__ __launch_bounds__(512, 4) void k_gemmT(
        const u16* __restrict__ feat,     // [NPAD,128] bf16 (xc or h)
        const u16* __restrict__ Wt,       // [9][128][128] bf16 (j-major, k contig)
        u16* __restrict__ Y) {            // [9][NPAD][128] bf16
    __shared__ __align__(16) u16 As[128 * 128];   // 32 KB
    __shared__ __align__(16) u16 Bs[128 * 128];   // 32 KB
    int tid = threadIdx.x;
    int bx = blockIdx.x;
    int mb = bx / 9, rp = bx - mb * 9;   // consecutive blocks share the feat tile (L2)
    int bm0 = mb * 128;
    int wave = tid >> 6, lane = tid & 63;
    int wm = (wave & 3) * 32, wn = (wave >> 2) * 64;
    int lrow = lane & 15, quad = lane >> 4;

    v4f accr[2][4];
    #pragma unroll
    for (int i = 0; i < 2; ++i)
        #pragma unroll
        for (int j = 0; j < 4; ++j) accr[i][j] = (v4f){0.f, 0.f, 0.f, 0.f};

    // single stage round: As <- feat tile, Bs <- plane rp of Wt (both 256 B/row)
    #pragma unroll
    for (int j = 0; j < 4; ++j) {
        int off = wave * 4096 + j * 1024 + lane * 16;   // byte offset, linear dest
        int row = off >> 8;                              // 256 B per row
        int cc = ((off >> 4) & 15) ^ (row & 15);         // inverse of read swizzle
        __builtin_amdgcn_global_load_lds(
            (gas_u32*)(feat + (size_t)(bm0 + row) * 128 + cc * 8),
            (las_u32*)(As + (off >> 1) - lane * 8), 16, 0, 0);
        __builtin_amdgcn_global_load_lds(
            (gas_u32*)(Wt + ((rp * 128 + row) << 7) + cc * 8),
            (las_u32*)(Bs + (off >> 1) - lane * 8), 16, 0, 0);
    }
    __syncthreads();                  // drains vmcnt (compiler-inserted)

    #pragma unroll
    for (int kk = 0; kk < 4; ++kk) {
        int chunk = kk * 4 + quad;
        v8s a[2], b[4];
        #pragma unroll
        for (int t = 0; t < 2; ++t) {
            int row = wm + t * 16 + lrow;
            a[t] = *(const v8s*)(As + row * 128 + (chunk ^ (row & 15)) * 8);
        }
        #pragma unroll
        for (int t = 0; t < 4; ++t) {
            int row = wn + t * 16 + lrow;
            b[t] = *(const v8s*)(Bs + row * 128 + (chunk ^ (row & 15)) * 8);
        }
        #pragma unroll
        for (int ti = 0; ti < 2; ++ti)
            #pragma unroll
            for (int tj = 0; tj < 4; ++tj)
                accr[ti][tj] = __builtin_amdgcn_mfma_f32_16x16x32_bf16(a[ti], b[tj], accr[ti][tj], 0, 0, 0);
    }

    // write full tile (including rows >= N_NODES: ZROW's zero row must land in Y)
    u16* yp = Y + ((size_t)rp * NPAD + bm0) * 128;
    #pragma unroll
    for (int ti = 0; ti < 2; ++ti)
        #pragma unroll
        for (int reg = 0; reg < 4; ++reg) {
            int rloc = wm + ti * 16 + quad * 4 + reg;
            #pragma unroll
            for (int tj = 0; tj < 4; ++tj) {
                int col = wn + tj * 16 + lrow;
                yp[(size_t)rloc * 128 + col] = f2bf(accr[ti][tj][reg]);
            }
        }
}

// ---------- output: out = relu( sum_r mean_r(Y) + Y_self + bias ) ----------
// Gather structure identical to the R8-measured agg (zero-row sentinel, u32 offsets,
// bfpair unpack), but reads Y planes and writes only the 12.8 MB output row
// (old agg: WRITE=100 MB, 8 stores + 8 cvt_pk -> now 1 store + 1 cvt_pk).
__global__ __launch_bounds__(256) void k_out(
        const u16* __restrict__ Y,        // [9][NPAD][128] bf16, row ZROW of each = 0
        const int* __restrict__ cnt, const u16* __restrict__ evalF,
        const u16* __restrict__ bias,     // [128] bf16 (bc + l*128)
        const u32* __restrict__ xdet,     // raw x for wave_detect
        u16* __restrict__ hout, void* __restrict__ fout, int final_out) {
    int wave = threadIdx.x >> 6, lane = threadIdx.x & 63;
    int node = blockIdx.x * 4 + wave;
    if (node >= N_NODES) return;
    int fl = wave_detect(xdet);          // uniform; used only if final_out
    u32 lane4 = (u32)lane * 4u;          // byte offset of this lane's dim pair
    int base = node * N_REL;

    // counts (broadcast, 2 x int4)
    int4 ca = ((const int4*)(cnt + base))[0];
    int4 cb = ((const int4*)(cnt + base))[1];
    int cs[8] = {ca.x, ca.y, ca.z, ca.w, cb.x, cb.y, cb.z, cb.w};
    // entries: first 4 slots of each bucket, 8 independent broadcast loads
    const u16* eb = evalF + (size_t)base * RCAP;
    ushort4 eg[8];
    #pragma unroll
    for (int r = 0; r < N_REL; ++r)
        eg[r] = *(const ushort4*)(eb + r * RCAP);

    // 32 gathers from the 8 relation planes (invalid -> zero row), unconditional acc
    const char* fb = (const char*)Y;
    v2f acc[N_REL];
    #pragma unroll
    for (int r = 0; r < N_REL; ++r) {
        int c = cs[r];
        u32 pb = (u32)r * PLSZ;
        u32 o0 = pb + ((u32)(c > 0 ? (int)eg[r].x : ZROW) << 8) + lane4;
        u32 o1 = pb + ((u32)(c > 1 ? (int)eg[r].y : ZROW) << 8) + lane4;
        u32 o2 = pb + ((u32)(c > 2 ? (int)eg[r].z : ZROW) << 8) + lane4;
        u32 o3 = pb + ((u32)(c > 3 ? (int)eg[r].w : ZROW) << 8) + lane4;
        u32 g0 = *(const u32*)(fb + o0);
        u32 g1 = *(const u32*)(fb + o1);
        u32 g2 = *(const u32*)(fb + o2);
        u32 g3 = *(const u32*)(fb + o3);
        acc[r] = (bfpair(g0) + bfpair(g1)) + (bfpair(g2) + bfpair(g3));
    }

    // rare tail: any bucket with c > 4 (wave-uniform condition)
    int cmax = cs[0];
    #pragma unroll
    for (int r = 1; r < N_REL; ++r) cmax = cs[r] > cmax ? cs[r] : cmax;
    if (cmax > 4) {
        #pragma unroll
        for (int r = 0; r < N_REL; ++r) {
            int c = cs[r] < RCAP ? cs[r] : RCAP;
            for (int j = 4; j < c; ++j) {
                u32 oj = (u32)r * PLSZ + ((u32)eb[r * RCAP + j] << 8) + lane4;
                acc[r] += bfpair(*(const u32*)(fb + oj));
            }
        }
    }

    // self plane + bias + means
    v2f sum = bfpair(*(const u32*)(fb + 8u * PLSZ + ((u32)node << 8) + lane4));
    sum += bfpair(*(const u32*)((const char*)bias + lane4));
    #pragma unroll
    for (int r = 0; r < N_REL; ++r) {
        int cc = cs[r] < RCAP ? cs[r] : RCAP;
        if (cc < 1) cc = 1;
        // v_rcp_f32: 2^-23 rel error, invisible under bf16 (2^-9) rounding
        float inv = __builtin_amdgcn_rcpf((float)cc);
        sum.x += acc[r].x * inv;
        sum.y += acc[r].y * inv;
    }
    float sx = fmaxf(sum.x, 0.f), sy = fmaxf(sum.y, 0.f);
    size_t oidx = (size_t)node * 128 + lane * 2;
    if (!final_out) {
        u32 pk;
        asm("v_cvt_pk_bf16_f32 %0, %1, %2" : "=v"(pk) : "v"(sx), "v"(sy));
        *(u32*)(hout + oidx) = pk;
    } else if (fl) {
        u32 pk;
        asm("v_cvt_pk_bf16_f32 %0, %1, %2" : "=v"(pk) : "v"(sx), "v"(sy));
        *(u32*)((u16*)fout + oidx) = pk;
    } else {
        ((float*)fout)[oidx]     = sx;
        ((float*)fout)[oidx + 1] = sy;
    }
}

// ---------------- launch ----------------
static inline size_t align_up(size_t x, size_t a) { return (x + a - 1) & ~(a - 1); }

extern "C" void kernel_launch(void* const* d_in, const int* in_sizes, int n_in,
                              void* d_out, int out_size, void* d_ws, size_t ws_size,
                              hipStream_t stream) {
    const int* ei = (const int*)d_in[1];
    const int* et = (const int*)d_in[2];

    char* ws = (char*)d_ws;
    size_t off = 0;
    u16* Wt     = (u16*)(ws + off);  off = align_up(off + (size_t)2 * NPLANE * 16384 * 2, 256);
    u16* bc     = (u16*)(ws + off);  off = align_up(off + 512, 256);
    u16* xc     = (u16*)(ws + off);  off = align_up(off + (size_t)NPAD * 128 * 2, 256);
    int* cnt    = (int*)(ws + off);  off = align_up(off + (size_t)N_NODES * N_REL * 4, 256);
    u16* evalF  = (u16*)(ws + off);  off = align_up(off + (size_t)N_NODES * N_REL * RCAP * 2, 256);
    u16* h      = (u16*)(ws + off);  off = align_up(off + (size_t)NPAD * 128 * 2, 256);
    u16* Y      = (u16*)(ws + off);  off += (size_t)NPLANE * NPAD * 128 * 2;   // ~156 MB total
    (void)in_sizes; (void)n_in; (void)out_size; (void)ws_size;   // ws >= 157 MB (verified r3/r4)

    hipMemsetAsync(cnt, 0, (size_t)N_NODES * N_REL * 4, stream);
    k_prep<<<B_RELEMB, 256, 0, stream>>>(d_in[0], ei, et, d_in[3], d_in[4], d_in[5],
                                         d_in[6], d_in[7], d_in[8], d_in[9],
                                         xc, h, Wt, bc, cnt, evalF, d_out);

    for (int l = 0; l < 2; ++l) {
        const u16* src = l ? h : xc;
        k_gemmT<<<(NPAD / 128) * 9, 512, 0, stream>>>(src, Wt + (size_t)l * NPLANE * 16384, Y);
        k_out<<<(N_NODES + 3) / 4, 256, 0, stream>>>(Y, cnt, evalF, bc + l * 128,
                                                     (const u32*)d_in[0], h, d_out, l);
    }
}

// Round 20
// 256.430 us; speedup vs baseline: 1.0803x; 1.0277x over previous
//
#include <hip/hip_runtime.h>
#include <stdint.h>

#define N_NODES 50000
#define N_EDGES 600000
#define N_REL   8
#define NPLANE  9                         // 8 relation planes + 1 self/root plane
#define NPAD    50048                     // 391 * 128
#define RCAP    16                        // per-(node,rel) bucket cap (Poisson(1.5): P(>16)~6e-13)
#define ZROW    N_NODES                   // sentinel zero row (written by k_prepA)
#define PLSZ    (NPAD * 256u)             // Y plane size in bytes (NPAD rows x 256 B)
#define NGEMMB  ((NPAD / 128) * 9)        // 3519 gemm blocks
#define NCFB    1172                      // 1172 blk * 512 thr >= 600K edges

typedef short v8s __attribute__((ext_vector_type(8)));
typedef float v4f __attribute__((ext_vector_type(4)));
typedef float v2f __attribute__((ext_vector_type(2)));
typedef unsigned short u16;
typedef unsigned int   u32;
typedef __attribute__((address_space(1))) const u32 gas_u32;
typedef __attribute__((address_space(3))) u32 las_u32;

__device__ __forceinline__ float bf2f(u16 u) {
    union { u32 i; float f; } t; t.i = ((u32)u) << 16; return t.f;
}
__device__ __forceinline__ u16 f2bf(float f) {
    union { float f; u32 i; } t; t.f = f;
    u32 lsb = (t.i >> 16) & 1u;
    t.i += 0x7fffu + lsb;            // round-to-nearest-even
    return (u16)(t.i >> 16);
}
// unpack a u32 holding 2 bf16 into (lo,hi) f32 pair: 1 shl + 1 and, no cvt
__device__ __forceinline__ v2f bfpair(u32 g) {
    union { u32 i; float f; } a, b;
    a.i = g << 16; b.i = g & 0xffff0000u;
    return (v2f){a.f, b.f};
}
__device__ __forceinline__ float load_f(const void* p, int i, int fl) {
    return fl ? bf2f(((const u16*)p)[i]) : ((const float*)p)[i];
}
// wave-local dtype detect: every wave reads x32[0..63] (L2-hot broadcast),
// ballots on "bits[14:7] look like a bf16 exponent of N(0,1) data".
__device__ __forceinline__ int wave_detect(const u32* __restrict__ x32) {
    u32 w = x32[threadIdx.x & 63];
    u32 e = (w >> 7) & 0xffu;
    unsigned long long m = __ballot(e >= 112u && e < 144u);
    return __popcll(m) >= 32;        // 1 = bf16, 0 = f32
}

// ---------- prepA: STREAMING ONLY (no CF) ----------
// R15 post-mortem: k_prep was 41 us at 2.5% VALU / 22% HBM — latency-bound purely on
// the CF atomic->scatter chain, which overlaps NOTHING in-stream. CF is moved into the
// gemmT1 launch (complementary resources: CF latency-bound, gemmT write-BW-bound).
// prepA keeps the streaming sections + zeroes cnt (kills the memset node).
// Wt layout: Wt[l][r][j][k] = W_l[r][k][j] (r<8); Wt[l][8][j][k] = root_l[k][j].
#define B_ZC    391                       // 391*256 int4 = 100096 >= 100000 (400K ints)
#define B_CONV  (B_ZC + 3125)             // 3125 blk * 256 thr * 8 elems = 6.4M exact
#define B_PREPW (B_CONV + 1153)           // 2*9*16384 = 294912 W elems + 256 bias
#define B_TOTAL (B_PREPW + 5)             // 4 relemb blocks + 1 zero-row block
__global__ void k_prepA(const void* __restrict__ x,
                        const void* __restrict__ W1, const void* __restrict__ r1,
                        const void* __restrict__ b1, const void* __restrict__ W2,
                        const void* __restrict__ r2, const void* __restrict__ b2,
                        const void* __restrict__ rel_emb,
                        u16* __restrict__ xc, u16* __restrict__ hbuf,
                        u16* __restrict__ Wt, u16* __restrict__ bc,
                        int* __restrict__ cnt, void* __restrict__ out) {
    int b = blockIdx.x, tid = threadIdx.x;
    int fl = wave_detect((const u32*)x);
    if (b < B_ZC) {
        int i4 = b * 256 + tid;
        if (i4 < 100000) ((int4*)cnt)[i4] = (int4){0, 0, 0, 0};
    } else if (b < B_CONV) {
        int g = (b - B_ZC) * 256 + tid;           // 8-elem group
        if (fl) {
            ((int4*)xc)[g] = ((const int4*)x)[g];
        } else {
            const float* xf = (const float*)x + g * 8;
            u16 o[8];
            #pragma unroll
            for (int j = 0; j < 8; ++j) o[j] = f2bf(xf[j]);
            *(int4*)(xc + g * 8) = *(const int4*)o;
        }
    } else if (b < B_PREPW) {
        int o = (b - B_CONV) * 256 + tid;
        if (o < 2 * NPLANE * 16384) {
            int l = o / (NPLANE * 16384);
            int rem = o - l * (NPLANE * 16384);
            int rr = rem >> 14;               // plane 0..8
            int j = (rem >> 7) & 127;        // output col
            int k = rem & 127;               // input dim
            float v = (rr < 8)
                ? load_f(l ? W2 : W1, rr * 16384 + k * 128 + j, fl)
                : load_f(l ? r2 : r1, k * 128 + j, fl);
            Wt[o] = f2bf(v);
        } else if (o < 2 * NPLANE * 16384 + 256) {
            int o2 = o - 2 * NPLANE * 16384;
            bc[o2] = f2bf(load_f((o2 >> 7) ? b2 : b1, o2 & 127, fl));
        }
    } else if (b < B_PREPW + 4) {
        int i = (b - B_PREPW) * 256 + tid;
        if (i < N_REL * 128) {
            size_t o = (size_t)N_NODES * 128 + i;
            if (fl) ((u16*)out)[o]   = ((const u16*)rel_emb)[i];
            else    ((float*)out)[o] = ((const float*)rel_emb)[i];
        }
    } else {
        // zero-row sentinels (row ZROW of both feature buffers) -> Y[r][ZROW] = 0@W = 0
        if (tid < 64)        ((u32*)(xc   + (size_t)ZROW * 128))[tid]      = 0;
        else if (tid < 128)  ((u32*)(hbuf + (size_t)ZROW * 128))[tid - 64] = 0;
    }
}

// ---------- shared gemm body: Y[rp] = feat @ Wt[rp] (K=128, no k-loop) ----------
// One stage + one barrier + 32 MFMA/wave per block; latency hidden by block turnover
// (R13 post-mortem: the 9-chunk K-loop variant was stall-bound at MfmaUtil 12.5%).
__device__ __forceinline__ void gemmT_body(int gbx,
        const u16* __restrict__ feat, const u16* __restrict__ Wt,
        u16* __restrict__ Y) {
    __shared__ __align__(16) u16 As[128 * 128];   // 32 KB
    __shared__ __align__(16) u16 Bs[128 * 128];   // 32 KB
    int tid = threadIdx.x;
    int mb = gbx / 9, rp = gbx - mb * 9;  // consecutive blocks share the feat tile (L2)
    int bm0 = mb * 128;
    int wave = tid >> 6, lane = tid & 63;
    int wm = (wave & 3) * 32, wn = (wave >> 2) * 64;
    int lrow = lane & 15, quad = lane >> 4;

    v4f accr[2][4];
    #pragma unroll
    for (int i = 0; i < 2; ++i)
        #pragma unroll
        for (int j = 0; j < 4; ++j) accr[i][j] = (v4f){0.f, 0.f, 0.f, 0.f};

    // single stage round: As <- feat tile, Bs <- plane rp of Wt (both 256 B/row)
    #pragma unroll
    for (int j = 0; j < 4; ++j) {
        int off = wave * 4096 + j * 1024 + lane * 16;   // byte offset, linear dest
        int row = off >> 8;                              // 256 B per row
        int cc = ((off >> 4) & 15) ^ (row & 15);         // inverse of read swizzle
        __builtin_amdgcn_global_load_lds(
            (gas_u32*)(feat + (size_t)(bm0 + row) * 128 + cc * 8),
            (las_u32*)(As + (off >> 1) - lane * 8), 16, 0, 0);
        __builtin_amdgcn_global_load_lds(
            (gas_u32*)(Wt + ((rp * 128 + row) << 7) + cc * 8),
            (las_u32*)(Bs + (off >> 1) - lane * 8), 16, 0, 0);
    }
    __syncthreads();                  // drains vmcnt (compiler-inserted)

    #pragma unroll
    for (int kk = 0; kk < 4; ++kk) {
        int chunk = kk * 4 + quad;
        v8s a[2], b[4];
        #pragma unroll
        for (int t = 0; t < 2; ++t) {
            int row = wm + t * 16 + lrow;
            a[t] = *(const v8s*)(As + row * 128 + (chunk ^ (row & 15)) * 8);
        }
        #pragma unroll
        for (int t = 0; t < 4; ++t) {
            int row = wn + t * 16 + lrow;
            b[t] = *(const v8s*)(Bs + row * 128 + (chunk ^ (row & 15)) * 8);
        }
        #pragma unroll
        for (int ti = 0; ti < 2; ++ti)
            #pragma unroll
            for (int tj = 0; tj < 4; ++tj)
                accr[ti][tj] = __builtin_amdgcn_mfma_f32_16x16x32_bf16(a[ti], b[tj], accr[ti][tj], 0, 0, 0);
    }

    // write full tile (including rows >= N_NODES: ZROW's zero row must land in Y)
    u16* yp = Y + ((size_t)rp * NPAD + bm0) * 128;
    #pragma unroll
    for (int ti = 0; ti < 2; ++ti)
        #pragma unroll
        for (int reg = 0; reg < 4; ++reg) {
            int rloc = wm + ti * 16 + quad * 4 + reg;
            #pragma unroll
            for (int tj = 0; tj < 4; ++tj) {
                int col = wn + tj * 16 + lrow;
                yp[(size_t)rloc * 128 + col] = f2bf(accr[ti][tj][reg]);
            }
        }
}

// ---------- layer-1 fused launch: gemmT blocks + CF blocks interleaved ----------
// CF (count+fill buckets) rides inside the gemmT1 launch: every 4th block (while CF
// blocks remain) is a CF block, so the dispatcher keeps a mix resident. gemmT is
// write-BW-bound, CF is latency-bound — complementary, CF ~free.
// k_out1 (next launch) is the first consumer of cnt/evalF.
__global__ __launch_bounds__(512, 4) void k_gemmT_cf(
        const u16* __restrict__ feat, const u16* __restrict__ Wt,
        u16* __restrict__ Y,
        const int* __restrict__ ei, const int* __restrict__ et,
        int* __restrict__ cnt, u16* __restrict__ evalF) {
    int bx = blockIdx.x;
    int phase = bx & 3, quarter = bx >> 2;
    if (phase == 0 && quarter < NCFB) {
        int i = quarter * 512 + threadIdx.x;
        if (i < N_EDGES) {
            int d = ei[N_EDGES + i];
            int bkt = d * N_REL + et[i];
            int pos = atomicAdd(&cnt[bkt], 1);
            if (pos < RCAP) evalF[(size_t)bkt * RCAP + pos] = (u16)ei[i];
        }
        return;
    }
    int cfbefore = (quarter >= NCFB) ? NCFB : (quarter + (phase > 0 ? 1 : 0));
    gemmT_body(bx - cfbefore, feat, Wt, Y);
}

// ---------- layer-2 plain gemmT ----------
__global__ __launch_bounds__(512, 4) void k_gemmT(
        const u16* __restrict__ feat, const u16* __restrict__ Wt,
        u16* __restrict__ Y) {
    gemmT_body(blockIdx.x, feat, Wt, Y);
}

// ---------- output: out = relu( sum_r mean_r(Y) + Y_self + bias ) ----------
// R15-measured 40.6 us (VALU 66%, HBM 31%). Unchanged this round.
__global__ __launch_bounds__(256) void k_out(
        const u16* __restrict__ Y,        // [9][NPAD][128] bf16, row ZROW of each = 0
        const int* __restrict__ cnt, const u16* __restrict__ evalF,
        const u16* __restrict__ bias,     // [128] bf16 (bc + l*128)
        const u32* __restrict__ xdet,     // raw x for wave_detect
        u16* __restrict__ hout, void* __restrict__ fout, int final_out) {
    int wave = threadIdx.x >> 6, lane = threadIdx.x & 63;
    int node = blockIdx.x * 4 + wave;
    if (node >= N_NODES) return;
    int fl = wave_detect(xdet);          // uniform; used only if final_out
    u32 lane4 = (u32)lane * 4u;          // byte offset of this lane's dim pair
    int base = node * N_REL;

    // counts (broadcast, 2 x int4)
    int4 ca = ((const int4*)(cnt + base))[0];
    int4 cb = ((const int4*)(cnt + base))[1];
    int cs[8] = {ca.x, ca.y, ca.z, ca.w, cb.x, cb.y, cb.z, cb.w};
    // entries: first 4 slots of each bucket, 8 independent broadcast loads
    const u16* eb = evalF + (size_t)base * RCAP;
    ushort4 eg[8];
    #pragma unroll
    for (int r = 0; r < N_REL; ++r)
        eg[r] = *(const ushort4*)(eb + r * RCAP);

    // 32 gathers from the 8 relation planes (invalid -> zero row), unconditional acc
    const char* fb = (const char*)Y;
    v2f acc[N_REL];
    #pragma unroll
    for (int r = 0; r < N_REL; ++r) {
        int c = cs[r];
        u32 pb = (u32)r * PLSZ;
        u32 o0 = pb + ((u32)(c > 0 ? (int)eg[r].x : ZROW) << 8) + lane4;
        u32 o1 = pb + ((u32)(c > 1 ? (int)eg[r].y : ZROW) << 8) + lane4;
        u32 o2 = pb + ((u32)(c > 2 ? (int)eg[r].z : ZROW) << 8) + lane4;
        u32 o3 = pb + ((u32)(c > 3 ? (int)eg[r].w : ZROW) << 8) + lane4;
        u32 g0 = *(const u32*)(fb + o0);
        u32 g1 = *(const u32*)(fb + o1);
        u32 g2 = *(const u32*)(fb + o2);
        u32 g3 = *(const u32*)(fb + o3);
        acc[r] = (bfpair(g0) + bfpair(g1)) + (bfpair(g2) + bfpair(g3));
    }

    // rare tail: any bucket with c > 4 (wave-uniform condition)
    int cmax = cs[0];
    #pragma unroll
    for (int r = 1; r < N_REL; ++r) cmax = cs[r] > cmax ? cs[r] : cmax;
    if (cmax > 4) {
        #pragma unroll
        for (int r = 0; r < N_REL; ++r) {
            int c = cs[r] < RCAP ? cs[r] : RCAP;
            for (int j = 4; j < c; ++j) {
                u32 oj = (u32)r * PLSZ + ((u32)eb[r * RCAP + j] << 8) + lane4;
                acc[r] += bfpair(*(const u32*)(fb + oj));
            }
        }
    }

    // self plane + bias + means
    v2f sum = bfpair(*(const u32*)(fb + 8u * PLSZ + ((u32)node << 8) + lane4));
    sum += bfpair(*(const u32*)((const char*)bias + lane4));
    #pragma unroll
    for (int r = 0; r < N_REL; ++r) {
        int cc = cs[r] < RCAP ? cs[r] : RCAP;
        if (cc < 1) cc = 1;
        // v_rcp_f32: 2^-23 rel error, invisible under bf16 (2^-9) rounding
        float inv = __builtin_amdgcn_rcpf((float)cc);
        sum.x += acc[r].x * inv;
        sum.y += acc[r].y * inv;
    }
    float sx = fmaxf(sum.x, 0.f), sy = fmaxf(sum.y, 0.f);
    size_t oidx = (size_t)node * 128 + lane * 2;
    if (!final_out) {
        u32 pk;
        asm("v_cvt_pk_bf16_f32 %0, %1, %2" : "=v"(pk) : "v"(sx), "v"(sy));
        *(u32*)(hout + oidx) = pk;
    } else if (fl) {
        u32 pk;
        asm("v_cvt_pk_bf16_f32 %0, %1, %2" : "=v"(pk) : "v"(sx), "v"(sy));
        *(u32*)((u16*)fout + oidx) = pk;
    } else {
        ((float*)fout)[oidx]     = sx;
        ((float*)fout)[oidx + 1] = sy;
    }
}

// ---------------- launch ----------------
static inline size_t align_up(size_t x, size_t a) { return (x + a - 1) & ~(a - 1); }

extern "C" void kernel_launch(void* const* d_in, const int* in_sizes, int n_in,
                              void* d_out, int out_size, void* d_ws, size_t ws_size,
                              hipStream_t stream) {
    const int* ei = (const int*)d_in[1];
    const int* et = (const int*)d_in[2];

    char* ws = (char*)d_ws;
    size_t off = 0;
    u16* Wt     = (u16*)(ws + off);  off = align_up(off + (size_t)2 * NPLANE * 16384 * 2, 256);
    u16* bc     = (u16*)(ws + off);  off = align_up(off + 512, 256);
    u16* xc     = (u16*)(ws + off);  off = align_up(off + (size_t)NPAD * 128 * 2, 256);
    int* cnt    = (int*)(ws + off);  off = align_up(off + (size_t)N_NODES * N_REL * 4, 256);
    u16* evalF  = (u16*)(ws + off);  off = align_up(off + (size_t)N_NODES * N_REL * RCAP * 2, 256);
    u16* h      = (u16*)(ws + off);  off = align_up(off + (size_t)NPAD * 128 * 2, 256);
    u16* Y      = (u16*)(ws + off);  off += (size_t)NPLANE * NPAD * 128 * 2;   // ~156 MB total
    (void)in_sizes; (void)n_in; (void)out_size; (void)ws_size;   // ws >= 157 MB (verified r3/r4)

    // streaming prep (also zeroes cnt -> no memset node)
    k_prepA<<<B_TOTAL, 256, 0, stream>>>(d_in[0], d_in[3], d_in[4], d_in[5],
                                         d_in[6], d_in[7], d_in[8], d_in[9],
                                         xc, h, Wt, bc, cnt, d_out);
    // layer 1: gemmT with CF blocks fused in (CF output first read by k_out below)
    k_gemmT_cf<<<NGEMMB + NCFB, 512, 0, stream>>>(xc, Wt, Y, ei, et, cnt, evalF);
    k_out<<<(N_NODES + 3) / 4, 256, 0, stream>>>(Y, cnt, evalF, bc,
                                                 (const u32*)d_in[0], h, d_out, 0);
    // layer 2
    k_gemmT<<<NGEMMB, 512, 0, stream>>>(h, Wt + (size_t)NPLANE * 16384, Y);
    k_out<<<(N_NODES + 3) / 4, 256, 0, stream>>>(Y, cnt, evalF, bc + 128,
                                                 (const u32*)d_in[0], h, d_out, 1);
}